// Round 6
// baseline (146.899 us; speedup 1.0000x reference)
//
#include <hip/hip_runtime.h>
#include <hip/hip_bf16.h>

#define N_ROWS 8192
#define DIM 256
#define NUM_CLASSES 64
#define NBLK 64                        // 8192/128 row/col blocks
#define NTRI (NBLK * (NBLK + 1) / 2)   // 2080 upper-triangle tiles
#define SCR_PITCH 36                   // 32 data + pad; 144B row stride (16B aligned)

typedef __bf16 bf16x8 __attribute__((ext_vector_type(8)));
typedef float f32x4 __attribute__((ext_vector_type(4)));

__device__ __forceinline__ unsigned short f2bf(float f) {
  unsigned int u = __float_as_uint(f);
  u += 0x7fffu + ((u >> 16) & 1u);   // round-to-nearest-even
  return (unsigned short)(u >> 16);
}
__device__ __forceinline__ float bf2f(unsigned short h) {
  return __uint_as_float(((unsigned int)h) << 16);
}

__device__ __forceinline__ void tri_decode(int q, int& I, int& J) {
  int i = (int)((129.0f - sqrtf(16641.0f - 8.0f * (float)q)) * 0.5f);
  while (i * (129 - i) / 2 > q) --i;
  while ((i + 1) * (128 - i) / 2 <= q) ++i;
  I = i;
  J = i + (q - i * (129 - i) / 2);
}

// Kernel 1: quantize to bf16, per-row sum-of-squares of the *quantized* values
// (keeps diagonal cos exact), scale s_i = sqrt((log2e/t)/ss_i). Block 0 zeroes
// the cross-kernel accumulator used by row_loss.
__global__ void __launch_bounds__(256) prep_kernel(
    const float* __restrict__ x, const float* __restrict__ tptr,
    unsigned short* __restrict__ xb, float* __restrict__ sv,
    float* __restrict__ gsum, unsigned int* __restrict__ gcnt) {
  if (blockIdx.x == 0 && threadIdx.x == 0) { *gsum = 0.f; *gcnt = 0u; }
  const int row = blockIdx.x * 4 + (threadIdx.x >> 6);
  const int lane = threadIdx.x & 63;
  const float4 v = *reinterpret_cast<const float4*>(x + (size_t)row * DIM + lane * 4);
  const unsigned short q0 = f2bf(v.x), q1 = f2bf(v.y), q2 = f2bf(v.z), q3 = f2bf(v.w);
  const float f0 = bf2f(q0), f1 = bf2f(q1), f2 = bf2f(q2), f3 = bf2f(q3);
  float ss = f0 * f0 + f1 * f1 + f2 * f2 + f3 * f3;
  ushort4 u4; u4.x = q0; u4.y = q1; u4.z = q2; u4.w = q3;
  *reinterpret_cast<ushort4*>(xb + (size_t)row * DIM + lane * 4) = u4;
  for (int m = 32; m; m >>= 1) ss += __shfl_xor(ss, m, 64);
  if (lane == 0) sv[row] = sqrtf(1.4426950408889634f / tptr[0] / ss);
}

// Kernel 2: upper-triangle 128x128 Gram tiles. NO LDS STAGING: A/B MFMA
// fragments are loaded directly from global (L2/L3-resident 4 MB matrix) in
// the exact fragment pattern (row lc, 16B at k0+quad*16 — one 64B sector per
// row across the 4 quads). 2-deep register ping-pong prefetch; the K-loop has
// ZERO barriers. Epilogue: lanes write 4-col partials to padded LDS scratch,
// one barrier, 128 owner threads finish rows via ds_read_b128.
__global__ void __launch_bounds__(256, 3) main_kernel(
    const unsigned short* __restrict__ xb, const float* __restrict__ sv,
    const int* __restrict__ lab, float* __restrict__ part) {
  const int q = blockIdx.x;
  int I, J;
  tri_decode(q, I, J);

  __shared__ alignas(16) float scr[2][128 * SCR_PITCH];  // 36,864 B
  __shared__ float colred[2][128][2];                    // 2 KiB
  __shared__ float rsv[128]; __shared__ int rlab[128];   // tile-row scales/labels
  __shared__ float csv[128]; __shared__ int clab[128];   // tile-col scales/labels

  const int tid = threadIdx.x;
  const int wave = tid >> 6;
  const int lane = tid & 63;
  const int quad = lane >> 4;
  const int lc = lane & 15;
  const int wrow = (wave >> 1) * 64;
  const int wcol = (wave & 1) * 64;
  const int ch = wave & 1;  // column half this wave covers
  const int rowBase = I * 128;
  const int colBase = J * 128;

  // stage row/col scales+labels early (no dependency on K-loop)
  if (tid < 128) {
    rsv[tid] = sv[rowBase + tid];
    rlab[tid] = lab[rowBase + tid];
    csv[tid] = sv[colBase + tid];
    clab[tid] = lab[colBase + tid];
  }

  // fragment base pointers: row (.. + lc), k-offset quad*8 elements
  const unsigned short* aBase =
      xb + (size_t)(rowBase + wrow + lc) * DIM + quad * 8;
  const unsigned short* bBase =
      xb + (size_t)(colBase + wcol + lc) * DIM + quad * 8;

  f32x4 acc[4][4];
  const f32x4 zero4 = {0.f, 0.f, 0.f, 0.f};
  for (int mi = 0; mi < 4; ++mi)
    for (int ni = 0; ni < 4; ++ni) acc[mi][ni] = zero4;

  bf16x8 afr[2][4], bfr[2][4];
#pragma unroll
  for (int mi = 0; mi < 4; ++mi)
    afr[0][mi] = *reinterpret_cast<const bf16x8*>(aBase + mi * 16 * DIM);
#pragma unroll
  for (int ni = 0; ni < 4; ++ni)
    bfr[0][ni] = *reinterpret_cast<const bf16x8*>(bBase + ni * 16 * DIM);

#pragma unroll
  for (int kb = 0; kb < 8; ++kb) {
    const int cur = kb & 1, nxt = cur ^ 1;
    if (kb < 7) {
      const int ko = (kb + 1) * 32;
#pragma unroll
      for (int mi = 0; mi < 4; ++mi)
        afr[nxt][mi] =
            *reinterpret_cast<const bf16x8*>(aBase + mi * 16 * DIM + ko);
#pragma unroll
      for (int ni = 0; ni < 4; ++ni)
        bfr[nxt][ni] =
            *reinterpret_cast<const bf16x8*>(bBase + ni * 16 * DIM + ko);
    }
#pragma unroll
    for (int mi = 0; mi < 4; ++mi)
#pragma unroll
      for (int ni = 0; ni < 4; ++ni)
        acc[mi][ni] = __builtin_amdgcn_mfma_f32_16x16x32_bf16(
            afr[cur][mi], bfr[cur][ni], acc[mi][ni], 0, 0, 0);
  }
  __syncthreads();  // rsv/csv visible; scr free to write

  float scol[4];
  int labc[4];
#pragma unroll
  for (int ni = 0; ni < 4; ++ni) {
    scol[ni] = csv[wcol + ni * 16 + lc];
    labc[ni] = clab[wcol + ni * 16 + lc];
  }
  float ctot[4] = {0.f, 0.f, 0.f, 0.f};
  float csame[4] = {0.f, 0.f, 0.f, 0.f};

#pragma unroll
  for (int mi = 0; mi < 4; ++mi) {
#pragma unroll
    for (int r = 0; r < 4; ++r) {
      const int lr = wrow + mi * 16 + quad * 4 + r;  // C/D: row=(lane>>4)*4+reg
      const float siv = rsv[lr];
      const int li = rlab[lr];
      float st = 0.f, sm = 0.f;
#pragma unroll
      for (int ni = 0; ni < 4; ++ni) {
        const float e = exp2f(acc[mi][ni][r] * (siv * scol[ni]));
        const float em = (li == labc[ni]) ? e : 0.f;
        st += e;
        sm += em;
        ctot[ni] += e;
        csame[ni] += em;
      }
      scr[0][lr * SCR_PITCH + ch * 16 + lc] = st;  // 4-col partial, unique slot
      scr[1][lr * SCR_PITCH + ch * 16 + lc] = sm;
    }
  }

  if (J > I) {  // column sums: reduce over the 16 rows this lane covered
#pragma unroll
    for (int ni = 0; ni < 4; ++ni) {
      float t2 = ctot[ni] + __shfl_xor(ctot[ni], 16, 64);
      t2 += __shfl_xor(t2, 32, 64);
      float s2 = csame[ni] + __shfl_xor(csame[ni], 16, 64);
      s2 += __shfl_xor(s2, 32, 64);
      if (quad == 0) {
        colred[0][wcol + ni * 16 + lc][wave >> 1] = t2;
        colred[1][wcol + ni * 16 + lc][wave >> 1] = s2;
      }
    }
  }
  __syncthreads();

  if (tid < 128) {  // owner thread per tile-row: finish and store
    const int base = tid * SCR_PITCH;
    f32x4 a0 = {0.f, 0.f, 0.f, 0.f}, a1 = {0.f, 0.f, 0.f, 0.f};
#pragma unroll
    for (int k = 0; k < 8; ++k)
      a0 += *reinterpret_cast<const f32x4*>(&scr[0][base + 4 * k]);
#pragma unroll
    for (int k = 0; k < 8; ++k)
      a1 += *reinterpret_cast<const f32x4*>(&scr[1][base + 4 * k]);
    const float st = a0[0] + a0[1] + a0[2] + a0[3];
    const float sm = a1[0] + a1[1] + a1[2] + a1[3];
    part[(size_t)J * N_ROWS + rowBase + tid] = st;
    part[(size_t)(64 + J) * N_ROWS + rowBase + tid] = sm;
    if (J > I) {
      part[(size_t)I * N_ROWS + colBase + tid] =
          colred[0][tid][0] + colred[0][tid][1];
      part[(size_t)(64 + I) * N_ROWS + colBase + tid] =
          colred[1][tid][0] + colred[1][tid][1];
    }
  }
}

// Kernel 3: per-row loss terms (label histogram in LDS), block sums
// accumulated device-scope; last block writes the final scalar.
__global__ void __launch_bounds__(256) row_loss_kernel(
    const float* __restrict__ part, const int* __restrict__ lab,
    float* __restrict__ gsum, unsigned int* __restrict__ gcnt,
    float* __restrict__ out) {
  __shared__ int h[NUM_CLASSES];
  if (threadIdx.x < NUM_CLASSES) h[threadIdx.x] = 0;
  __syncthreads();
  for (int i = threadIdx.x; i < N_ROWS; i += 256) atomicAdd(&h[lab[i]], 1);
  __syncthreads();

  const int row = blockIdx.x * 256 + threadIdx.x;
  float st = 0.f, sm = 0.f;
#pragma unroll 8
  for (int b = 0; b < 64; ++b) {
    st += part[(size_t)b * N_ROWS + row];
    sm += part[(size_t)(64 + b) * N_ROWS + row];
  }
  const int c = h[lab[row]];
  const float pos = sm + (float)(N_ROWS - c);
  const float neg = (st - sm) + (float)c;
  float term = logf(neg) - logf(pos);
  for (int m = 32; m; m >>= 1) term += __shfl_xor(term, m, 64);
  __shared__ float wsum[4];
  const int lane = threadIdx.x & 63;
  const int wave = threadIdx.x >> 6;
  if (lane == 0) wsum[wave] = term;
  __syncthreads();
  if (threadIdx.x == 0) {
    const float bs = wsum[0] + wsum[1] + wsum[2] + wsum[3];
    atomicAdd(gsum, bs);
    __threadfence();
    const unsigned int t = atomicAdd(gcnt, 1u);
    if (t == (unsigned int)(N_ROWS / 256 - 1)) {  // last block to arrive
      const float total = atomicAdd(gsum, 0.0f);  // coherent read
      out[0] = total * (1.0f / (float)N_ROWS);
    }
  }
}

extern "C" void kernel_launch(void* const* d_in, const int* in_sizes, int n_in,
                              void* d_out, int out_size, void* d_ws, size_t ws_size,
                              hipStream_t stream) {
  const float* x = (const float*)d_in[0];
  const int* lab = (const int*)d_in[1];
  const float* t = (const float*)d_in[2];
  float* out = (float*)d_out;

  char* ws = (char*)d_ws;
  unsigned short* xb = (unsigned short*)ws;                      // 4 MiB bf16 X
  float* sv = (float*)(ws + (4u << 20));                         // 32 KiB scales
  float* part = (float*)(ws + (4u << 20) + (32u << 10));         // 4 MiB partials
  float* gsum = (float*)(ws + (8u << 20) + (32u << 10));
  unsigned int* gcnt = (unsigned int*)(ws + (8u << 20) + (32u << 10) + 8);

  prep_kernel<<<N_ROWS / 4, 256, 0, stream>>>(x, t, xb, sv, gsum, gcnt);
  main_kernel<<<NTRI, 256, 0, stream>>>(xb, sv, lab, part);
  row_loss_kernel<<<N_ROWS / 256, 256, 0, stream>>>(part, lab, gsum, gcnt, out);
}

// Round 7
// 144.892 us; speedup vs baseline: 1.0139x; 1.0139x over previous
//
#include <hip/hip_runtime.h>

#define N_ROWS 8192
#define DIM 256
#define NUM_CLASSES 64
#define NBLK 64                        // 8192/128 row/col blocks
#define NTRI (NBLK * (NBLK + 1) / 2)   // 2080 upper-triangle tiles
#define SCR_PITCH 36                   // 32 data + pad; 144B row stride

typedef float f32x4 __attribute__((ext_vector_type(4)));

__device__ __forceinline__ void gload_lds16(const void* g, void* l) {
  __builtin_amdgcn_global_load_lds(
      (const __attribute__((address_space(1))) unsigned int*)g,
      (__attribute__((address_space(3))) unsigned int*)l, 16, 0, 0);
}

__device__ __forceinline__ void tri_decode(int q, int& I, int& J) {
  int i = (int)((129.0f - sqrtf(16641.0f - 8.0f * (float)q)) * 0.5f);
  while (i * (129 - i) / 2 > q) --i;
  while ((i + 1) * (128 - i) / 2 <= q) ++i;
  I = i;
  J = i + (q - i * (129 - i) / 2);
}

// Kernel 1: quantize to OCP fp8 e4m3 (HW cvt, RNE), per-row sum-of-squares of
// the *quantized* values (keeps diagonal cos exact), s_i = sqrt((log2e/t)/ss),
// label histogram via global atomics (counts pre-zeroed by memset).
__global__ void __launch_bounds__(256) prep_kernel(
    const float* __restrict__ x, const int* __restrict__ lab,
    const float* __restrict__ tptr, unsigned int* __restrict__ xq,
    float* __restrict__ sv, int* __restrict__ counts,
    float* __restrict__ gsum, unsigned int* __restrict__ gcnt) {
  if (blockIdx.x == 0 && threadIdx.x == 0) { *gsum = 0.f; *gcnt = 0u; }
  const int row = blockIdx.x * 4 + (threadIdx.x >> 6);
  const int lane = threadIdx.x & 63;
  const float4 v = *reinterpret_cast<const float4*>(x + (size_t)row * DIM + lane * 4);
  int p = __builtin_amdgcn_cvt_pk_fp8_f32(v.x, v.y, 0, false);   // bytes 0,1
  p = __builtin_amdgcn_cvt_pk_fp8_f32(v.z, v.w, p, true);        // bytes 2,3
  const float f0 = __builtin_amdgcn_cvt_f32_fp8(p, 0);
  const float f1 = __builtin_amdgcn_cvt_f32_fp8(p, 1);
  const float f2 = __builtin_amdgcn_cvt_f32_fp8(p, 2);
  const float f3 = __builtin_amdgcn_cvt_f32_fp8(p, 3);
  float ss = f0 * f0 + f1 * f1 + f2 * f2 + f3 * f3;
  xq[(size_t)row * 64 + lane] = (unsigned int)p;
  for (int m = 32; m; m >>= 1) ss += __shfl_xor(ss, m, 64);
  if (lane == 0) {
    sv[row] = sqrtf(1.4426950408889634f / tptr[0] / ss);
    atomicAdd(&counts[lab[row]], 1);
  }
}

// Kernel 2: upper-triangle 128x128 Gram tiles, fp8 MFMA 16x16x32. FULL-K LDS:
// both 128x256 fp8 tiles (32KB+32KB) staged ONCE per tile via global_load_lds
// (one vmcnt-drain barrier), then a barrier-free 8-step K-loop of ds_read_b64
// + MFMA. LDS rows are XOR-swizzled in 16B chunks (seg ^= row&15) on the
// GLOBAL source side to break the 256B-stride bank conflict. Epilogue (same
// verified mapping as bf16): exp2 + padded-LDS row reduction + col partials.
__global__ void __launch_bounds__(256, 2) main_kernel(
    const unsigned char* __restrict__ xb, const float* __restrict__ sv,
    const int* __restrict__ lab, float* __restrict__ part) {
  const int q = blockIdx.x;
  int I, J;
  tri_decode(q, I, J);
  const int rowBase = I * 128;
  const int colBase = J * 128;

  __shared__ alignas(16) unsigned char ldsbuf[65536];  // A: [0,32K) B: [32K,64K)
  __shared__ float colred[2][128][2];
  __shared__ float rsv[128]; __shared__ int rlab[128];
  __shared__ float csv[128]; __shared__ int clab[128];
  unsigned char* Al = ldsbuf;
  unsigned char* Bl = ldsbuf + 32768;
  float* scr0 = reinterpret_cast<float*>(ldsbuf);            // 18432 B
  float* scr1 = reinterpret_cast<float*>(ldsbuf + 18432);    // 18432 B

  const int tid = threadIdx.x;
  const int wave = tid >> 6;
  const int lane = tid & 63;
  const int quad = lane >> 4;
  const int lc = lane & 15;
  const int wrow = (wave >> 1) * 64;
  const int wcol = (wave & 1) * 64;
  const int ch = wave & 1;
  const int lh = lane >> 4, l15 = lane & 15;

  if (tid < 128) {
    rsv[tid] = sv[rowBase + tid];
    rlab[tid] = lab[rowBase + tid];
    csv[tid] = sv[colBase + tid];
    clab[tid] = lab[colBase + tid];
  }

  // ---- stage both tiles, swizzled: LDS chunk (r, m) <- global (r, m^(r&15)) ----
  const unsigned char* Ag = xb + (size_t)rowBase * DIM;
  const unsigned char* Bg = xb + (size_t)colBase * DIM;
#pragma unroll
  for (int i = 0; i < 8; ++i) {
    const int r = wave * 32 + i * 4 + lh;        // local row this lane stages
    const int gseg = l15 ^ (r & 15);
    gload_lds16(Ag + (size_t)r * 256 + gseg * 16, Al + (wave * 32 + i * 4) * 256);
    gload_lds16(Bg + (size_t)r * 256 + gseg * 16, Bl + (wave * 32 + i * 4) * 256);
  }
  __syncthreads();  // one vmcnt drain per tile

  // ---- barrier-free K loop ----
  f32x4 acc[4][4];
  const f32x4 zero4 = {0.f, 0.f, 0.f, 0.f};
  for (int mi = 0; mi < 4; ++mi)
    for (int ni = 0; ni < 4; ++ni) acc[mi][ni] = zero4;

  const int qh = quad >> 1, h8 = (quad & 1) * 8;
  // fragment addr: row r' (r'&15 == lc), seg = kb*2+qh, swizzled seg = seg^lc
  int aOff[4], bOff[4];
#pragma unroll
  for (int mi = 0; mi < 4; ++mi)
    aOff[mi] = (wrow + mi * 16 + lc) * 256 + h8;
#pragma unroll
  for (int ni = 0; ni < 4; ++ni)
    bOff[ni] = (wcol + ni * 16 + lc) * 256 + h8;

#pragma unroll
  for (int kb = 0; kb < 8; ++kb) {
    const int swz = ((kb * 2 + qh) ^ lc) << 4;
    long afr[4], bfr[4];
#pragma unroll
    for (int mi = 0; mi < 4; ++mi)
      afr[mi] = *reinterpret_cast<const long*>(Al + aOff[mi] + swz);
#pragma unroll
    for (int ni = 0; ni < 4; ++ni)
      bfr[ni] = *reinterpret_cast<const long*>(Bl + bOff[ni] + swz);
#pragma unroll
    for (int mi = 0; mi < 4; ++mi)
#pragma unroll
      for (int ni = 0; ni < 4; ++ni)
        acc[mi][ni] = __builtin_amdgcn_mfma_f32_16x16x32_fp8_fp8(
            afr[mi], bfr[ni], acc[mi][ni], 0, 0, 0);
  }
  __syncthreads();  // all ds_reads done; ldsbuf becomes epilogue scratch

  // ---- epilogue (identical mapping to verified bf16 version) ----
  float scol[4];
  int labc[4];
#pragma unroll
  for (int ni = 0; ni < 4; ++ni) {
    scol[ni] = csv[wcol + ni * 16 + lc];
    labc[ni] = clab[wcol + ni * 16 + lc];
  }
  float ctot[4] = {0.f, 0.f, 0.f, 0.f};
  float csame[4] = {0.f, 0.f, 0.f, 0.f};

#pragma unroll
  for (int mi = 0; mi < 4; ++mi) {
#pragma unroll
    for (int r = 0; r < 4; ++r) {
      const int lr = wrow + mi * 16 + quad * 4 + r;  // C/D: row=(lane>>4)*4+reg
      const float siv = rsv[lr];
      const int li = rlab[lr];
      float st = 0.f, sm = 0.f;
#pragma unroll
      for (int ni = 0; ni < 4; ++ni) {
        const float e = exp2f(acc[mi][ni][r] * (siv * scol[ni]));
        const float em = (li == labc[ni]) ? e : 0.f;
        st += e;
        sm += em;
        ctot[ni] += e;
        csame[ni] += em;
      }
      scr0[lr * SCR_PITCH + ch * 16 + lc] = st;
      scr1[lr * SCR_PITCH + ch * 16 + lc] = sm;
    }
  }

  if (J > I) {
#pragma unroll
    for (int ni = 0; ni < 4; ++ni) {
      float t2 = ctot[ni] + __shfl_xor(ctot[ni], 16, 64);
      t2 += __shfl_xor(t2, 32, 64);
      float s2 = csame[ni] + __shfl_xor(csame[ni], 16, 64);
      s2 += __shfl_xor(s2, 32, 64);
      if (quad == 0) {
        colred[0][wcol + ni * 16 + lc][wave >> 1] = t2;
        colred[1][wcol + ni * 16 + lc][wave >> 1] = s2;
      }
    }
  }
  __syncthreads();

  if (tid < 128) {
    const int base = tid * SCR_PITCH;
    f32x4 a0 = {0.f, 0.f, 0.f, 0.f}, a1 = {0.f, 0.f, 0.f, 0.f};
#pragma unroll
    for (int k = 0; k < 8; ++k)
      a0 += *reinterpret_cast<const f32x4*>(&scr0[base + 4 * k]);
#pragma unroll
    for (int k = 0; k < 8; ++k)
      a1 += *reinterpret_cast<const f32x4*>(&scr1[base + 4 * k]);
    const float st = a0[0] + a0[1] + a0[2] + a0[3];
    const float sm = a1[0] + a1[1] + a1[2] + a1[3];
    part[(size_t)J * N_ROWS + rowBase + tid] = st;
    part[(size_t)(64 + J) * N_ROWS + rowBase + tid] = sm;
    if (J > I) {
      part[(size_t)I * N_ROWS + colBase + tid] =
          colred[0][tid][0] + colred[0][tid][1];
      part[(size_t)(64 + I) * N_ROWS + colBase + tid] =
          colred[1][tid][0] + colred[1][tid][1];
    }
  }
}

// Kernel 3: per-row loss terms (counts precomputed in prep); device-scope
// accumulation; last block writes the scalar.
__global__ void __launch_bounds__(128) row_loss_kernel(
    const float* __restrict__ part, const int* __restrict__ lab,
    const int* __restrict__ counts, float* __restrict__ gsum,
    unsigned int* __restrict__ gcnt, float* __restrict__ out) {
  const int row = blockIdx.x * 128 + threadIdx.x;
  float st = 0.f, sm = 0.f;
#pragma unroll 8
  for (int b = 0; b < 64; ++b) {
    st += part[(size_t)b * N_ROWS + row];
    sm += part[(size_t)(64 + b) * N_ROWS + row];
  }
  const int c = counts[lab[row]];
  const float pos = sm + (float)(N_ROWS - c);
  const float neg = (st - sm) + (float)c;
  float term = logf(neg) - logf(pos);
  for (int m = 32; m; m >>= 1) term += __shfl_xor(term, m, 64);
  __shared__ float wsum[2];
  const int lane = threadIdx.x & 63;
  const int wave = threadIdx.x >> 6;
  if (lane == 0) wsum[wave] = term;
  __syncthreads();
  if (threadIdx.x == 0) {
    atomicAdd(gsum, wsum[0] + wsum[1]);
    __threadfence();
    const unsigned int t = atomicAdd(gcnt, 1u);
    if (t == (unsigned int)(N_ROWS / 128 - 1)) {  // last block
      const float total = atomicAdd(gsum, 0.0f);  // coherent read
      out[0] = total * (1.0f / (float)N_ROWS);
    }
  }
}

extern "C" void kernel_launch(void* const* d_in, const int* in_sizes, int n_in,
                              void* d_out, int out_size, void* d_ws, size_t ws_size,
                              hipStream_t stream) {
  const float* x = (const float*)d_in[0];
  const int* lab = (const int*)d_in[1];
  const float* t = (const float*)d_in[2];
  float* out = (float*)d_out;

  char* ws = (char*)d_ws;
  unsigned int* xq = (unsigned int*)ws;                          // 2 MiB fp8 X
  float* sv = (float*)(ws + (2u << 20));                         // 32 KiB scales
  float* part = (float*)(ws + (2u << 20) + (32u << 10));         // 4 MiB partials
  int* counts = (int*)(ws + (6u << 20) + (32u << 10));           // 256 B
  float* gsum = (float*)(ws + (6u << 20) + (33u << 10));
  unsigned int* gcnt = (unsigned int*)(ws + (6u << 20) + (33u << 10) + 8);

  hipMemsetAsync(counts, 0, NUM_CLASSES * sizeof(int), stream);
  prep_kernel<<<N_ROWS / 4, 256, 0, stream>>>(x, lab, t, xq, sv, counts, gsum, gcnt);
  main_kernel<<<NTRI, 256, 0, stream>>>((const unsigned char*)xq, sv, lab, part);
  row_loss_kernel<<<N_ROWS / 128, 128, 0, stream>>>(part, lab, counts, gsum, gcnt, out);
}

// Round 8
// 106.202 us; speedup vs baseline: 1.3832x; 1.3643x over previous
//
#include <hip/hip_runtime.h>

#define N_ROWS 8192
#define DIM 256
#define NUM_CLASSES 64
#define NBLK 64                        // 8192/128 row/col blocks
#define NTRI (NBLK * (NBLK + 1) / 2)   // 2080 upper-triangle tiles
#define SCR_PITCH 36                   // 32 data + pad; 144B row stride

typedef float f32x4 __attribute__((ext_vector_type(4)));

__device__ __forceinline__ void gload_lds16(const void* g, void* l) {
  __builtin_amdgcn_global_load_lds(
      (const __attribute__((address_space(1))) unsigned int*)g,
      (__attribute__((address_space(3))) unsigned int*)l, 16, 0, 0);
}

__device__ __forceinline__ void tri_decode(int q, int& I, int& J) {
  int i = (int)((129.0f - sqrtf(16641.0f - 8.0f * (float)q)) * 0.5f);
  while (i * (129 - i) / 2 > q) --i;
  while ((i + 1) * (128 - i) / 2 <= q) ++i;
  I = i;
  J = i + (q - i * (129 - i) / 2);
}

// Kernel 1: quantize to OCP fp8 e4m3 (HW cvt), per-row sum-of-squares of the
// *quantized* values (keeps diagonal cos exact), s_i = sqrt((log2e/t)/ss).
// NO histogram, NO global atomics (R7's 42us lesson). Block 0 zeroes gsum/gcnt.
__global__ void __launch_bounds__(256) prep_kernel(
    const float* __restrict__ x, const float* __restrict__ tptr,
    unsigned int* __restrict__ xq, float* __restrict__ sv,
    float* __restrict__ gsum, unsigned int* __restrict__ gcnt) {
  if (blockIdx.x == 0 && threadIdx.x == 0) { *gsum = 0.f; *gcnt = 0u; }
  const int row = blockIdx.x * 4 + (threadIdx.x >> 6);
  const int lane = threadIdx.x & 63;
  const float4 v = *reinterpret_cast<const float4*>(x + (size_t)row * DIM + lane * 4);
  int p = __builtin_amdgcn_cvt_pk_fp8_f32(v.x, v.y, 0, false);   // bytes 0,1
  p = __builtin_amdgcn_cvt_pk_fp8_f32(v.z, v.w, p, true);        // bytes 2,3
  const float f0 = __builtin_amdgcn_cvt_f32_fp8(p, 0);
  const float f1 = __builtin_amdgcn_cvt_f32_fp8(p, 1);
  const float f2 = __builtin_amdgcn_cvt_f32_fp8(p, 2);
  const float f3 = __builtin_amdgcn_cvt_f32_fp8(p, 3);
  float ss = f0 * f0 + f1 * f1 + f2 * f2 + f3 * f3;
  xq[(size_t)row * 64 + lane] = (unsigned int)p;
  for (int m = 32; m; m >>= 1) ss += __shfl_xor(ss, m, 64);
  if (lane == 0) sv[row] = sqrtf(1.4426950408889634f / tptr[0] / ss);
}

// Kernel 2: upper-triangle 128x128 Gram tiles, fp8 MFMA 16x16x32. FULL-K LDS:
// both 128x256 fp8 tiles (32KB+32KB) staged once per tile (one vmcnt-drain
// barrier), then a barrier-free 8-step K-loop of swizzled ds_read_b64 + MFMA.
// Epilogue: exp2 + padded-LDS row reduction; (S_tot,S_same) stored as float2.
__global__ void __launch_bounds__(256, 2) main_kernel(
    const unsigned char* __restrict__ xb, const float* __restrict__ sv,
    const int* __restrict__ lab, float2* __restrict__ part) {
  const int q = blockIdx.x;
  int I, J;
  tri_decode(q, I, J);
  const int rowBase = I * 128;
  const int colBase = J * 128;

  __shared__ alignas(16) unsigned char ldsbuf[65536];  // A: [0,32K) B: [32K,64K)
  __shared__ float colred[2][128][2];
  __shared__ float rsv[128]; __shared__ int rlab[128];
  __shared__ float csv[128]; __shared__ int clab[128];
  unsigned char* Al = ldsbuf;
  unsigned char* Bl = ldsbuf + 32768;
  float* scr0 = reinterpret_cast<float*>(ldsbuf);            // 18432 B
  float* scr1 = reinterpret_cast<float*>(ldsbuf + 18432);    // 18432 B

  const int tid = threadIdx.x;
  const int wave = tid >> 6;
  const int lane = tid & 63;
  const int quad = lane >> 4;
  const int lc = lane & 15;
  const int wrow = (wave >> 1) * 64;
  const int wcol = (wave & 1) * 64;
  const int ch = wave & 1;
  const int lh = lane >> 4, l15 = lane & 15;

  if (tid < 128) {
    rsv[tid] = sv[rowBase + tid];
    rlab[tid] = lab[rowBase + tid];
    csv[tid] = sv[colBase + tid];
    clab[tid] = lab[colBase + tid];
  }

  // ---- stage both tiles, swizzled: LDS chunk (r, m) <- global (r, m^(r&15)) ----
  const unsigned char* Ag = xb + (size_t)rowBase * DIM;
  const unsigned char* Bg = xb + (size_t)colBase * DIM;
#pragma unroll
  for (int i = 0; i < 8; ++i) {
    const int r = wave * 32 + i * 4 + lh;        // local row this lane stages
    const int gseg = l15 ^ (r & 15);
    gload_lds16(Ag + (size_t)r * 256 + gseg * 16, Al + (wave * 32 + i * 4) * 256);
    gload_lds16(Bg + (size_t)r * 256 + gseg * 16, Bl + (wave * 32 + i * 4) * 256);
  }
  __syncthreads();  // one vmcnt drain per tile

  // ---- barrier-free K loop ----
  f32x4 acc[4][4];
  const f32x4 zero4 = {0.f, 0.f, 0.f, 0.f};
  for (int mi = 0; mi < 4; ++mi)
    for (int ni = 0; ni < 4; ++ni) acc[mi][ni] = zero4;

  const int qh = quad >> 1, h8 = (quad & 1) * 8;
  int aOff[4], bOff[4];
#pragma unroll
  for (int mi = 0; mi < 4; ++mi)
    aOff[mi] = (wrow + mi * 16 + lc) * 256 + h8;
#pragma unroll
  for (int ni = 0; ni < 4; ++ni)
    bOff[ni] = (wcol + ni * 16 + lc) * 256 + h8;

#pragma unroll
  for (int kb = 0; kb < 8; ++kb) {
    const int swz = ((kb * 2 + qh) ^ lc) << 4;
    long afr[4], bfr[4];
#pragma unroll
    for (int mi = 0; mi < 4; ++mi)
      afr[mi] = *reinterpret_cast<const long*>(Al + aOff[mi] + swz);
#pragma unroll
    for (int ni = 0; ni < 4; ++ni)
      bfr[ni] = *reinterpret_cast<const long*>(Bl + bOff[ni] + swz);
#pragma unroll
    for (int mi = 0; mi < 4; ++mi)
#pragma unroll
      for (int ni = 0; ni < 4; ++ni)
        acc[mi][ni] = __builtin_amdgcn_mfma_f32_16x16x32_fp8_fp8(
            afr[mi], bfr[ni], acc[mi][ni], 0, 0, 0);
  }
  __syncthreads();  // all ds_reads done; ldsbuf becomes epilogue scratch

  // ---- epilogue ----
  float scol[4];
  int labc[4];
#pragma unroll
  for (int ni = 0; ni < 4; ++ni) {
    scol[ni] = csv[wcol + ni * 16 + lc];
    labc[ni] = clab[wcol + ni * 16 + lc];
  }
  float ctot[4] = {0.f, 0.f, 0.f, 0.f};
  float csame[4] = {0.f, 0.f, 0.f, 0.f};

#pragma unroll
  for (int mi = 0; mi < 4; ++mi) {
#pragma unroll
    for (int r = 0; r < 4; ++r) {
      const int lr = wrow + mi * 16 + quad * 4 + r;  // C/D: row=(lane>>4)*4+reg
      const float siv = rsv[lr];
      const int li = rlab[lr];
      float st = 0.f, sm = 0.f;
#pragma unroll
      for (int ni = 0; ni < 4; ++ni) {
        const float e = exp2f(acc[mi][ni][r] * (siv * scol[ni]));
        const float em = (li == labc[ni]) ? e : 0.f;
        st += e;
        sm += em;
        ctot[ni] += e;
        csame[ni] += em;
      }
      scr0[lr * SCR_PITCH + ch * 16 + lc] = st;
      scr1[lr * SCR_PITCH + ch * 16 + lc] = sm;
    }
  }

  if (J > I) {
#pragma unroll
    for (int ni = 0; ni < 4; ++ni) {
      float t2 = ctot[ni] + __shfl_xor(ctot[ni], 16, 64);
      t2 += __shfl_xor(t2, 32, 64);
      float s2 = csame[ni] + __shfl_xor(csame[ni], 16, 64);
      s2 += __shfl_xor(s2, 32, 64);
      if (quad == 0) {
        colred[0][wcol + ni * 16 + lc][wave >> 1] = t2;
        colred[1][wcol + ni * 16 + lc][wave >> 1] = s2;
      }
    }
  }
  __syncthreads();

  if (tid < 128) {
    const int base = tid * SCR_PITCH;
    f32x4 a0 = {0.f, 0.f, 0.f, 0.f}, a1 = {0.f, 0.f, 0.f, 0.f};
#pragma unroll
    for (int k = 0; k < 8; ++k)
      a0 += *reinterpret_cast<const f32x4*>(&scr0[base + 4 * k]);
#pragma unroll
    for (int k = 0; k < 8; ++k)
      a1 += *reinterpret_cast<const f32x4*>(&scr1[base + 4 * k]);
    float2 v;
    v.x = a0[0] + a0[1] + a0[2] + a0[3];
    v.y = a1[0] + a1[1] + a1[2] + a1[3];
    part[(size_t)J * N_ROWS + rowBase + tid] = v;
    if (J > I) {
      float2 w;
      w.x = colred[0][tid][0] + colred[0][tid][1];
      w.y = colred[1][tid][0] + colred[1][tid][1];
      part[(size_t)I * N_ROWS + colBase + tid] = w;
    }
  }
}

// Kernel 3: per-row loss terms; label histogram per block in LDS (proven R5
// pattern — no global hot-spot atomics); device-scope finalize.
__global__ void __launch_bounds__(256) row_loss_kernel(
    const float2* __restrict__ part, const int* __restrict__ lab,
    float* __restrict__ gsum, unsigned int* __restrict__ gcnt,
    float* __restrict__ out) {
  __shared__ int h[NUM_CLASSES];
  if (threadIdx.x < NUM_CLASSES) h[threadIdx.x] = 0;
  __syncthreads();
  for (int i = threadIdx.x; i < N_ROWS; i += 256) atomicAdd(&h[lab[i]], 1);
  __syncthreads();

  const int row = blockIdx.x * 256 + threadIdx.x;
  float st = 0.f, sm = 0.f;
#pragma unroll 8
  for (int b = 0; b < 64; ++b) {
    const float2 v = part[(size_t)b * N_ROWS + row];
    st += v.x;
    sm += v.y;
  }
  const int c = h[lab[row]];
  const float pos = sm + (float)(N_ROWS - c);
  const float neg = (st - sm) + (float)c;
  float term = logf(neg) - logf(pos);
  for (int m = 32; m; m >>= 1) term += __shfl_xor(term, m, 64);
  __shared__ float wsum[4];
  const int lane = threadIdx.x & 63;
  const int wave = threadIdx.x >> 6;
  if (lane == 0) wsum[wave] = term;
  __syncthreads();
  if (threadIdx.x == 0) {
    atomicAdd(gsum, wsum[0] + wsum[1] + wsum[2] + wsum[3]);
    __threadfence();
    const unsigned int t = atomicAdd(gcnt, 1u);
    if (t == (unsigned int)(N_ROWS / 256 - 1)) {  // last block
      const float total = atomicAdd(gsum, 0.0f);  // coherent read
      out[0] = total * (1.0f / (float)N_ROWS);
    }
  }
}

extern "C" void kernel_launch(void* const* d_in, const int* in_sizes, int n_in,
                              void* d_out, int out_size, void* d_ws, size_t ws_size,
                              hipStream_t stream) {
  const float* x = (const float*)d_in[0];
  const int* lab = (const int*)d_in[1];
  const float* t = (const float*)d_in[2];
  float* out = (float*)d_out;

  char* ws = (char*)d_ws;
  unsigned int* xq = (unsigned int*)ws;                          // 2 MiB fp8 X
  float* sv = (float*)(ws + (2u << 20));                         // 32 KiB scales
  float2* part = (float2*)(ws + (2u << 20) + (32u << 10));       // 4 MiB partials
  float* gsum = (float*)(ws + (6u << 20) + (32u << 10));
  unsigned int* gcnt = (unsigned int*)(ws + (6u << 20) + (32u << 10) + 8);

  prep_kernel<<<N_ROWS / 4, 256, 0, stream>>>(x, t, xq, sv, gsum, gcnt);
  main_kernel<<<NTRI, 256, 0, stream>>>((const unsigned char*)xq, sv, lab, part);
  row_loss_kernel<<<N_ROWS / 256, 256, 0, stream>>>(part, lab, gsum, gcnt, out);
}

// Round 9
// 98.615 us; speedup vs baseline: 1.4896x; 1.0769x over previous
//
#include <hip/hip_runtime.h>

#define N_ROWS 8192
#define DIM 256
#define NUM_CLASSES 64
#define NBLK 64                        // 8192/128 row/col blocks
#define NTRI (NBLK * (NBLK + 1) / 2)   // 2080 upper-triangle tiles
#define SCR_PITCH 36                   // 32 data + pad; 144B row stride

typedef float f32x4 __attribute__((ext_vector_type(4)));

__device__ __forceinline__ void gload_lds16(const void* g, void* l) {
  __builtin_amdgcn_global_load_lds(
      (const __attribute__((address_space(1))) unsigned int*)g,
      (__attribute__((address_space(3))) unsigned int*)l, 16, 0, 0);
}

__device__ __forceinline__ void tri_decode(int q, int& I, int& J) {
  int i = (int)((129.0f - sqrtf(16641.0f - 8.0f * (float)q)) * 0.5f);
  while (i * (129 - i) / 2 > q) --i;
  while ((i + 1) * (128 - i) / 2 <= q) ++i;
  I = i;
  J = i + (q - i * (129 - i) / 2);
}

// Kernel 1: quantize to OCP fp8 e4m3 (HW cvt), per-row sum-of-squares of the
// *quantized* values (keeps diagonal cos exact), s_i = sqrt((log2e/t)/ss).
// No histogram, no global hot-spot atomics. Block 0 zeroes gsum/gcnt.
__global__ void __launch_bounds__(256) prep_kernel(
    const float* __restrict__ x, const float* __restrict__ tptr,
    unsigned int* __restrict__ xq, float* __restrict__ sv,
    float* __restrict__ gsum, unsigned int* __restrict__ gcnt) {
  if (blockIdx.x == 0 && threadIdx.x == 0) { *gsum = 0.f; *gcnt = 0u; }
  const int row = blockIdx.x * 4 + (threadIdx.x >> 6);
  const int lane = threadIdx.x & 63;
  const float4 v = *reinterpret_cast<const float4*>(x + (size_t)row * DIM + lane * 4);
  int p = __builtin_amdgcn_cvt_pk_fp8_f32(v.x, v.y, 0, false);   // bytes 0,1
  p = __builtin_amdgcn_cvt_pk_fp8_f32(v.z, v.w, p, true);        // bytes 2,3
  const float f0 = __builtin_amdgcn_cvt_f32_fp8(p, 0);
  const float f1 = __builtin_amdgcn_cvt_f32_fp8(p, 1);
  const float f2 = __builtin_amdgcn_cvt_f32_fp8(p, 2);
  const float f3 = __builtin_amdgcn_cvt_f32_fp8(p, 3);
  float ss = f0 * f0 + f1 * f1 + f2 * f2 + f3 * f3;
  xq[(size_t)row * 64 + lane] = (unsigned int)p;
  for (int m = 32; m; m >>= 1) ss += __shfl_xor(ss, m, 64);
  if (lane == 0) sv[row] = sqrtf(1.4426950408889634f / tptr[0] / ss);
}

// Kernel 2: upper-triangle 128x128 Gram tiles, fp8 MFMA 16x16x32. K-SPLIT
// staging: K half [0,128) of both tiles (16KB+16KB) staged, 4-kb compute,
// then half [128,256) into the same buffer. LDS = 40,960 B -> 3 blocks/CU
// (vs full-K's 2). 16B chunks XOR-swizzled (c = s ^ (lc&7)) on the global
// source side: optimal 4-phase b64 reads, only the free 2-way alias.
// Epilogue: exp2 + padded-LDS row reduction; (S_tot,S_same) as float2.
__global__ void __launch_bounds__(256, 3) main_kernel(
    const unsigned char* __restrict__ xb, const float* __restrict__ sv,
    const int* __restrict__ lab, float2* __restrict__ part) {
  const int q = blockIdx.x;
  int I, J;
  tri_decode(q, I, J);
  const int rowBase = I * 128;
  const int colBase = J * 128;

  __shared__ alignas(16) unsigned char buf[36864];  // staging 32KB; scr 36KB alias
  __shared__ float colred[2][128][2];
  __shared__ float rsv[128]; __shared__ int rlab[128];
  __shared__ float csv[128]; __shared__ int clab[128];
  unsigned char* Al = buf;            // 128 rows x 128 B (one K half)
  unsigned char* Bl = buf + 16384;
  float* scr0 = reinterpret_cast<float*>(buf);           // 18432 B
  float* scr1 = reinterpret_cast<float*>(buf + 18432);   // 18432 B

  const int tid = threadIdx.x;
  const int wave = tid >> 6;
  const int lane = tid & 63;
  const int quad = lane >> 4;
  const int lc = lane & 15;
  const int wrow = (wave >> 1) * 64;
  const int wcol = (wave & 1) * 64;
  const int ch = wave & 1;
  const int r8 = lane >> 3;      // staging: 8 rows per instruction
  const int c8 = lane & 7;       // 8 x 16B chunks per half-row

  if (tid < 128) {
    rsv[tid] = sv[rowBase + tid];
    rlab[tid] = lab[rowBase + tid];
    csv[tid] = sv[colBase + tid];
    clab[tid] = lab[colBase + tid];
  }

  const unsigned char* Ag = xb + (size_t)rowBase * DIM;
  const unsigned char* Bg = xb + (size_t)colBase * DIM;

  // stage one K-half of A and B: LDS (r,c) <- global (r, h*128 + (c^(r&7))*16)
#define STAGE_HALF(h)                                                         \
  {                                                                           \
    _Pragma("unroll") for (int i = 0; i < 4; ++i) {                           \
      const int r = wave * 32 + i * 8 + r8;                                   \
      const int gc = c8 ^ (r & 7);                                            \
      gload_lds16(Ag + (size_t)r * 256 + (h)*128 + gc * 16,                   \
                  Al + (wave * 32 + i * 8) * 128);                            \
      gload_lds16(Bg + (size_t)r * 256 + (h)*128 + gc * 16,                   \
                  Bl + (wave * 32 + i * 8) * 128);                            \
    }                                                                         \
  }

  f32x4 acc[4][4];
  const f32x4 zero4 = {0.f, 0.f, 0.f, 0.f};
  for (int mi = 0; mi < 4; ++mi)
    for (int ni = 0; ni < 4; ++ni) acc[mi][ni] = zero4;

  const int qh = quad >> 1, h8 = (quad & 1) * 8;
  int aOff[4], bOff[4];
#pragma unroll
  for (int mi = 0; mi < 4; ++mi)
    aOff[mi] = (wrow + mi * 16 + lc) * 128 + h8;
#pragma unroll
  for (int ni = 0; ni < 4; ++ni)
    bOff[ni] = (wcol + ni * 16 + lc) * 128 + h8;

  STAGE_HALF(0)
  __syncthreads();  // half-0 staged
#pragma unroll
  for (int half = 0; half < 2; ++half) {
#pragma unroll
    for (int kbl = 0; kbl < 4; ++kbl) {
      const int swz = (((kbl * 2 + qh) ^ (lc & 7)) << 4);
      long afr[4], bfr[4];
#pragma unroll
      for (int mi = 0; mi < 4; ++mi)
        afr[mi] = *reinterpret_cast<const long*>(Al + aOff[mi] + swz);
#pragma unroll
      for (int ni = 0; ni < 4; ++ni)
        bfr[ni] = *reinterpret_cast<const long*>(Bl + bOff[ni] + swz);
#pragma unroll
      for (int mi = 0; mi < 4; ++mi)
#pragma unroll
        for (int ni = 0; ni < 4; ++ni)
          acc[mi][ni] = __builtin_amdgcn_mfma_f32_16x16x32_fp8_fp8(
              afr[mi], bfr[ni], acc[mi][ni], 0, 0, 0);
    }
    __syncthreads();  // readers done with this half
    if (half == 0) {
      STAGE_HALF(1)
      __syncthreads();  // half-1 staged
    }
  }
#undef STAGE_HALF

  // ---- epilogue (buf now reusable as scratch) ----
  float scol[4];
  int labc[4];
#pragma unroll
  for (int ni = 0; ni < 4; ++ni) {
    scol[ni] = csv[wcol + ni * 16 + lc];
    labc[ni] = clab[wcol + ni * 16 + lc];
  }
  float ctot[4] = {0.f, 0.f, 0.f, 0.f};
  float csame[4] = {0.f, 0.f, 0.f, 0.f};

#pragma unroll
  for (int mi = 0; mi < 4; ++mi) {
#pragma unroll
    for (int r = 0; r < 4; ++r) {
      const int lr = wrow + mi * 16 + quad * 4 + r;  // C/D: row=(lane>>4)*4+reg
      const float siv = rsv[lr];
      const int li = rlab[lr];
      float st = 0.f, sm = 0.f;
#pragma unroll
      for (int ni = 0; ni < 4; ++ni) {
        const float e = exp2f(acc[mi][ni][r] * (siv * scol[ni]));
        const float em = (li == labc[ni]) ? e : 0.f;
        st += e;
        sm += em;
        ctot[ni] += e;
        csame[ni] += em;
      }
      scr0[lr * SCR_PITCH + ch * 16 + lc] = st;
      scr1[lr * SCR_PITCH + ch * 16 + lc] = sm;
    }
  }

  if (J > I) {
#pragma unroll
    for (int ni = 0; ni < 4; ++ni) {
      float t2 = ctot[ni] + __shfl_xor(ctot[ni], 16, 64);
      t2 += __shfl_xor(t2, 32, 64);
      float s2 = csame[ni] + __shfl_xor(csame[ni], 16, 64);
      s2 += __shfl_xor(s2, 32, 64);
      if (quad == 0) {
        colred[0][wcol + ni * 16 + lc][wave >> 1] = t2;
        colred[1][wcol + ni * 16 + lc][wave >> 1] = s2;
      }
    }
  }
  __syncthreads();

  if (tid < 128) {
    const int base = tid * SCR_PITCH;
    f32x4 a0 = {0.f, 0.f, 0.f, 0.f}, a1 = {0.f, 0.f, 0.f, 0.f};
#pragma unroll
    for (int k = 0; k < 8; ++k)
      a0 += *reinterpret_cast<const f32x4*>(&scr0[base + 4 * k]);
#pragma unroll
    for (int k = 0; k < 8; ++k)
      a1 += *reinterpret_cast<const f32x4*>(&scr1[base + 4 * k]);
    float2 v;
    v.x = a0[0] + a0[1] + a0[2] + a0[3];
    v.y = a1[0] + a1[1] + a1[2] + a1[3];
    part[(size_t)J * N_ROWS + rowBase + tid] = v;
    if (J > I) {
      float2 w;
      w.x = colred[0][tid][0] + colred[0][tid][1];
      w.y = colred[1][tid][0] + colred[1][tid][1];
      part[(size_t)I * N_ROWS + colBase + tid] = w;
    }
  }
}

// Kernel 3: per-row loss terms; label histogram per block in LDS; device-scope
// finalize by last-arriving block.
__global__ void __launch_bounds__(256) row_loss_kernel(
    const float2* __restrict__ part, const int* __restrict__ lab,
    float* __restrict__ gsum, unsigned int* __restrict__ gcnt,
    float* __restrict__ out) {
  __shared__ int h[NUM_CLASSES];
  if (threadIdx.x < NUM_CLASSES) h[threadIdx.x] = 0;
  __syncthreads();
  for (int i = threadIdx.x; i < N_ROWS; i += 256) atomicAdd(&h[lab[i]], 1);
  __syncthreads();

  const int row = blockIdx.x * 256 + threadIdx.x;
  float st = 0.f, sm = 0.f;
#pragma unroll 8
  for (int b = 0; b < 64; ++b) {
    const float2 v = part[(size_t)b * N_ROWS + row];
    st += v.x;
    sm += v.y;
  }
  const int c = h[lab[row]];
  const float pos = sm + (float)(N_ROWS - c);
  const float neg = (st - sm) + (float)c;
  float term = logf(neg) - logf(pos);
  for (int m = 32; m; m >>= 1) term += __shfl_xor(term, m, 64);
  __shared__ float wsum[4];
  const int lane = threadIdx.x & 63;
  const int wave = threadIdx.x >> 6;
  if (lane == 0) wsum[wave] = term;
  __syncthreads();
  if (threadIdx.x == 0) {
    atomicAdd(gsum, wsum[0] + wsum[1] + wsum[2] + wsum[3]);
    __threadfence();
    const unsigned int t = atomicAdd(gcnt, 1u);
    if (t == (unsigned int)(N_ROWS / 256 - 1)) {  // last block
      const float total = atomicAdd(gsum, 0.0f);  // coherent read
      out[0] = total * (1.0f / (float)N_ROWS);
    }
  }
}

extern "C" void kernel_launch(void* const* d_in, const int* in_sizes, int n_in,
                              void* d_out, int out_size, void* d_ws, size_t ws_size,
                              hipStream_t stream) {
  const float* x = (const float*)d_in[0];
  const int* lab = (const int*)d_in[1];
  const float* t = (const float*)d_in[2];
  float* out = (float*)d_out;

  char* ws = (char*)d_ws;
  unsigned int* xq = (unsigned int*)ws;                          // 2 MiB fp8 X
  float* sv = (float*)(ws + (2u << 20));                         // 32 KiB scales
  float2* part = (float2*)(ws + (2u << 20) + (32u << 10));       // 4 MiB partials
  float* gsum = (float*)(ws + (6u << 20) + (32u << 10));
  unsigned int* gcnt = (unsigned int*)(ws + (6u << 20) + (32u << 10) + 8);

  prep_kernel<<<N_ROWS / 4, 256, 0, stream>>>(x, t, xq, sv, gsum, gcnt);
  main_kernel<<<NTRI, 256, 0, stream>>>((const unsigned char*)xq, sv, lab, part);
  row_loss_kernel<<<N_ROWS / 256, 256, 0, stream>>>(part, lab, gsum, gcnt, out);
}